// Round 8
// baseline (136.255 us; speedup 1.0000x reference)
//
#include <hip/hip_runtime.h>

// Problem constants (fixed by the reference file).
#define T_LEN 8192
#define D_CH  2048
#define CC    128                 // chunks along T
#define L_C   (T_LEN / CC)        // 64 steps per chunk

// v = z*v + x (x real), z complex.
__device__ __forceinline__ void step_real(float zre, float zim,
                                          float& vre, float& vim, float x) {
    float nre = fmaf(zre, vre, fmaf(-zim, vim, x));
    float nim = fmaf(zre, vim, zim * vre);
    vre = nre; vim = nim;
}

__device__ __forceinline__ void load_z(const float* __restrict__ size_,
                                       const float* __restrict__ theta_,
                                       int d, float& zre, float& zim) {
    float e = expf(size_[d]);
    float r = expf(-e);
    float s, c;
    sincosf(theta_[d], &s, &c);
    zre = r * c;
    zim = r * s;
}

// Kernel 1: per (chunk, channel) local scan from v=0; publish ONLY the
// chunk-final complex value. Pure 64 MB coalesced read.
__global__ __launch_bounds__(256) void k_sums(const float* __restrict__ x,
                                              const float* __restrict__ size_,
                                              const float* __restrict__ theta_,
                                              float2* __restrict__ sums) {
    const int d = blockIdx.x * 256 + threadIdx.x;
    const int c = blockIdx.y;
    float zre, zim;
    load_z(size_, theta_, d, zre, zim);

    const float* xp = x + (size_t)c * L_C * D_CH + d;
    float vre = 0.f, vim = 0.f;
#pragma unroll 16
    for (int k = 0; k < L_C; ++k)
        step_real(zre, zim, vre, vim, xp[(size_t)k * D_CH]);
    sums[c * D_CH + d] = make_float2(vre, vim);
}

// Kernel 2: per-channel exclusive scan over the CC chunk sums with z^L.
// In-place: sums[c][d] := carry INTO chunk c. 8 blocks, ~2 MB L2 traffic,
// loads batched 16-deep so the serial chain overlaps latency.
__global__ __launch_bounds__(256) void k_carry(const float* __restrict__ size_,
                                               const float* __restrict__ theta_,
                                               float2* __restrict__ ws) {
    const int d = blockIdx.x * 256 + threadIdx.x;
    float e  = expf(size_[d]);
    float rL = expf(-(float)L_C * e);          // underflow->0 is correct
    float sL, cL;
    sincosf((float)L_C * theta_[d], &sL, &cL);
    const float zLre = rL * cL, zLim = rL * sL;

    float cre = 0.f, cim = 0.f;
    for (int base = 0; base < CC; base += 16) {
        float2 loc[16];
#pragma unroll
        for (int j = 0; j < 16; ++j)
            loc[j] = ws[(base + j) * D_CH + d];    // batch-issued loads
#pragma unroll
        for (int j = 0; j < 16; ++j) {
            ws[(base + j) * D_CH + d] = make_float2(cre, cim);
            float nre = fmaf(zLre, cre, fmaf(-zLim, cim, loc[j].x));
            float nim = fmaf(zLre, cim, fmaf(zLim, cre, loc[j].y));
            cre = nre; cim = nim;
        }
    }
}

// Kernel 3: pure stream. Read the single carry row, scan the chunk re-reading
// x (L3-warm from k1), nontemporal-write the output.
template <bool ILV>
__global__ __launch_bounds__(256) void k_scan(const float* __restrict__ x,
                                              const float* __restrict__ size_,
                                              const float* __restrict__ theta_,
                                              const float2* __restrict__ carry,
                                              float* __restrict__ out) {
    const int d = blockIdx.x * 256 + threadIdx.x;
    const int c = blockIdx.y;

    // Issue the carry load first (independent of the transcendental work).
    const float2 cv = carry[c * D_CH + d];

    float zre, zim;
    load_z(size_, theta_, d, zre, zim);

    float vre = cv.x, vim = cv.y;
    const float* xp = x + (size_t)c * L_C * D_CH + d;
    if (ILV) {
        float2* o2 = (float2*)out + (size_t)c * L_C * D_CH + d;
#pragma unroll 16
        for (int k = 0; k < L_C; ++k) {
            step_real(zre, zim, vre, vim, xp[(size_t)k * D_CH]);
            float2 v = make_float2(vre, vim);
            __builtin_nontemporal_store(v.x, &o2[(size_t)k * D_CH].x);
            __builtin_nontemporal_store(v.y, &o2[(size_t)k * D_CH].y);
        }
    } else {
        float* o = out + (size_t)c * L_C * D_CH + d;
#pragma unroll 16
        for (int k = 0; k < L_C; ++k) {
            step_real(zre, zim, vre, vim, xp[(size_t)k * D_CH]);
            __builtin_nontemporal_store(vre, &o[(size_t)k * D_CH]);
        }
    }
}

extern "C" void kernel_launch(void* const* d_in, const int* in_sizes, int n_in,
                              void* d_out, int out_size, void* d_ws, size_t ws_size,
                              hipStream_t stream) {
    const float* x  = (const float*)d_in[0];
    const float* sz = (const float*)d_in[1];
    const float* th = (const float*)d_in[2];
    float2* sums = (float2*)d_ws;                 // CC * D_CH * 8 B = 2 MB
    float* out = (float*)d_out;
    const bool realOnly = (out_size == T_LEN * D_CH);

    dim3 blk(256);
    dim3 grid(D_CH / 256, CC);                    // 1024 blocks = 4/CU

    k_sums<<<grid, blk, 0, stream>>>(x, sz, th, sums);
    k_carry<<<dim3(D_CH / 256), blk, 0, stream>>>(sz, th, sums);
    if (realOnly)
        k_scan<false><<<grid, blk, 0, stream>>>(x, sz, th, sums, out);
    else
        k_scan<true><<<grid, blk, 0, stream>>>(x, sz, th, sums, out);
}